// Round 4
// baseline (87.058 us; speedup 1.0000x reference)
//
#include <hip/hip_runtime.h>

#define NXg 2048
#define NYg 2048
#define TAB_N 4096            // intervals; nodes = TAB_N + 1
#define TAB_LO   -8.0f
#define TAB_SCALE 256.0f      // 1/h
#define INV_D 100.0f          // 1/DX == 1/DY

// Kernel 1: tabulate a(u) = W3^T tanh(W2^T tanh(u*W1)) at 4097 nodes.
// One lane per (node, hidden-unit j); wave64 = 2 nodes x 32 j.
__global__ void build_table(const float* __restrict__ W1,
                            const float* __restrict__ W2,
                            const float* __restrict__ W3,
                            float* __restrict__ tab) {
    const int lane   = threadIdx.x & 63;
    const int half   = lane >> 5;
    const int j      = lane & 31;
    const int waveid = (blockIdx.x * blockDim.x + threadIdx.x) >> 6;
    const int node   = waveid * 2 + half;
    const int node_c = node <= TAB_N ? node : TAB_N;

    const float x = TAB_LO + (float)node_c * (1.0f / TAB_SCALE);
    const float t = tanhf(x * W1[j]);

    float z = 0.0f;
    #pragma unroll
    for (int k = 0; k < 32; ++k) {
        const float h1k = __shfl(t, (half << 5) | k);
        z = fmaf(h1k, W2[k * 32 + j], z);
    }
    float v = tanhf(z) * W3[j];
    #pragma unroll
    for (int m = 1; m < 32; m <<= 1) v += __shfl_xor(v, m);

    if (j == 0 && node <= TAB_N) tab[node] = v;
}

// Kernel 2: 5-point flux stencil, a(u) via LDS table lerp.
// Table stored as two separate float arrays (value, delta) so each random
// gather is a 4-byte-stride ds_read_b32 over all 32 banks (the float2/b64
// layout hit only even bank-pairs -> ~2x worse serialization on random idx).
// 8 consecutive elements per thread; 1024 threads/block, 512 blocks (2/CU).
__launch_bounds__(1024)
__global__ void flux_kernel(const float* __restrict__ u,
                            const float* __restrict__ tab,
                            const float* __restrict__ Dp,
                            const float* __restrict__ BCp,
                            const float* __restrict__ St,
                            float* __restrict__ out) {
    __shared__ float sval[TAB_N];   // f(node)
    __shared__ float sdel[TAB_N];   // f(node+1) - f(node)
    for (int t = threadIdx.x; t < TAB_N; t += 1024) {
        const float a0 = tab[t];
        const float a1 = tab[t + 1];
        sval[t] = a0;
        sdel[t] = a1 - a0;
    }
    __syncthreads();

    const float d      = Dp[0];
    const float bc0    = BCp[0];
    const float bc1    = BCp[1];
    const float s0     = St[0];
    const float s1     = St[1];
    const float two_s0 = s0 + s0;

    const int gid  = blockIdx.x * blockDim.x + threadIdx.x;
    const int base = gid << 3;           // first of 8 consecutive elements (one row)
    const int i    = base >> 11;         // row (NY = 2048)
    const int j    = base & (NYg - 1);   // column of first element

    const float4 c0 = *reinterpret_cast<const float4*>(u + base);
    const float4 c1 = *reinterpret_cast<const float4*>(u + base + 4);
    float4 L0, L1, R0, R1;
    if (i > 0) {
        L0 = *reinterpret_cast<const float4*>(u + base - NYg);
        L1 = *reinterpret_cast<const float4*>(u + base - NYg + 4);
    } else {
        L0 = L1 = make_float4(bc0, bc0, bc0, bc0);
    }
    if (i < NXg - 1) {
        R0 = *reinterpret_cast<const float4*>(u + base + NYg);
        R1 = *reinterpret_cast<const float4*>(u + base + NYg + 4);
    } else {
        R0 = R1 = make_float4(bc1, bc1, bc1, bc1);
    }
    const float um1 = (j > 0)       ? u[base - 1] : bc0;
    const float up8 = (j + 8 < NYg) ? u[base + 8] : bc1;

    const float uc[8] = {c0.x, c0.y, c0.z, c0.w, c1.x, c1.y, c1.z, c1.w};
    const float ul[8] = {L0.x, L0.y, L0.z, L0.w, L1.x, L1.y, L1.z, L1.w};
    const float ur[8] = {R0.x, R0.y, R0.z, R0.w, R1.x, R1.y, R1.z, R1.w};
    const float ub[8] = {um1,  c0.x, c0.y, c0.z, c0.w, c1.x, c1.y, c1.z};
    const float ut[8] = {c0.y, c0.z, c0.w, c1.x, c1.y, c1.z, c1.w, up8};

    float res[8];
    #pragma unroll
    for (int e = 0; e < 8; ++e) {
        // a(u): t = (u - LO)*SCALE = u*256 + 2048
        float t = fmaf(uc[e], TAB_SCALE, 2048.0f);
        t = fminf(fmaxf(t, 0.0f), 4095.999f);
        const int   i0 = (int)t;
        const float fr = t - (float)i0;
        const float a  = fmaf(fr, sdel[i0], sval[i0]);

        const float ap = fmaxf(a, 0.0f);
        const float am = fminf(a, 0.0f);
        const float cp = fmaf(ap,  INV_D, d);   // d + relu(a)/DX
        const float cm = fmaf(am, -INV_D, d);   // d - (-relu(-a))/DX

        // gl+gb = 2*s0*uc + s1*(ul+ub); gr+gt = 2*s0*uc + s1*(ur+ut)
        const float g2 = two_s0 * uc[e];
        const float gp = fmaf(s1, ul[e] + ub[e], g2);
        const float gm = fmaf(s1, ur[e] + ut[e], g2);
        res[e] = fmaf(cm, gm, cp * gp);
    }
    float4 o0 = make_float4(res[0], res[1], res[2], res[3]);
    float4 o1 = make_float4(res[4], res[5], res[6], res[7]);
    *reinterpret_cast<float4*>(out + base)     = o0;
    *reinterpret_cast<float4*>(out + base + 4) = o1;
}

extern "C" void kernel_launch(void* const* d_in, const int* in_sizes, int n_in,
                              void* d_out, int out_size, void* d_ws, size_t ws_size,
                              hipStream_t stream) {
    const float* u  = (const float*)d_in[0];
    const float* W1 = (const float*)d_in[1];
    const float* W2 = (const float*)d_in[2];
    const float* W3 = (const float*)d_in[3];
    const float* D  = (const float*)d_in[4];
    const float* BC = (const float*)d_in[5];
    const float* St = (const float*)d_in[6];
    float* out = (float*)d_out;
    float* tab = (float*)d_ws;   // (TAB_N+1) floats of scratch

    hipLaunchKernelGGL(build_table, dim3((TAB_N / 8) + 1), dim3(256), 0, stream,
                       W1, W2, W3, tab);

    const int n_threads = (NXg * NYg) / 8;           // 524,288
    hipLaunchKernelGGL(flux_kernel, dim3(n_threads / 1024), dim3(1024), 0, stream,
                       u, tab, D, BC, St, out);
}

// Round 6
// 85.694 us; speedup vs baseline: 1.0159x; 1.0159x over previous
//
#include <hip/hip_runtime.h>

#define NXg 2048
#define NYg 2048
#define TAB_N 2048            // intervals; nodes = TAB_N + 1
#define TAB_LO   -8.0f
#define TAB_SCALE 128.0f      // 1/h, h = 16/2048
#define TAB_BIAS 1024.0f      // -TAB_LO * TAB_SCALE
#define INV_D 100.0f          // 1/DX == 1/DY

typedef float f32x4 __attribute__((ext_vector_type(4)));  // clang-native vec for nontemporal builtins

// Kernel 1: tabulate a(u) = W3^T tanh(W2^T tanh(u*W1)) at 2049 nodes.
// One lane per (node, hidden-unit j); wave64 = 2 nodes x 32 j.
__global__ void build_table(const float* __restrict__ W1,
                            const float* __restrict__ W2,
                            const float* __restrict__ W3,
                            float* __restrict__ tab) {
    const int lane   = threadIdx.x & 63;
    const int half   = lane >> 5;
    const int j      = lane & 31;
    const int waveid = (blockIdx.x * blockDim.x + threadIdx.x) >> 6;
    const int node   = waveid * 2 + half;
    const int node_c = node <= TAB_N ? node : TAB_N;

    const float x = TAB_LO + (float)node_c * (1.0f / TAB_SCALE);
    const float t = tanhf(x * W1[j]);

    float z = 0.0f;
    #pragma unroll
    for (int k = 0; k < 32; ++k) {
        const float h1k = __shfl(t, (half << 5) | k);
        z = fmaf(h1k, W2[k * 32 + j], z);
    }
    float v = tanhf(z) * W3[j];
    #pragma unroll
    for (int m = 1; m < 32; m <<= 1) v += __shfl_xor(v, m);

    if (j == 0 && node <= TAB_N) tab[node] = v;
}

// Kernel 2: 5-point flux stencil, a(u) via LDS table lerp (value/delta in
// separate 4B-stride arrays -> random gather spreads over all 32 banks).
// 8 consecutive elements per thread; 1024 threads/block, 512 blocks (2/CU).
// Output stored nontemporally: write-once stream, keep L2 for u-row reuse.
__launch_bounds__(1024)
__global__ void flux_kernel(const float* __restrict__ u,
                            const float* __restrict__ tab,
                            const float* __restrict__ Dp,
                            const float* __restrict__ BCp,
                            const float* __restrict__ St,
                            float* __restrict__ out) {
    __shared__ float sval[TAB_N];   // f(node)
    __shared__ float sdel[TAB_N];   // f(node+1) - f(node)
    #pragma unroll
    for (int s = 0; s < 2; ++s) {
        const int t = threadIdx.x + s * 1024;
        const float a0 = tab[t];
        const float a1 = tab[t + 1];
        sval[t] = a0;
        sdel[t] = a1 - a0;
    }
    __syncthreads();

    const float d      = Dp[0];
    const float bc0    = BCp[0];
    const float bc1    = BCp[1];
    const float s0     = St[0];
    const float s1     = St[1];
    const float two_s0 = s0 + s0;

    const int gid  = blockIdx.x * blockDim.x + threadIdx.x;
    const int base = gid << 3;           // first of 8 consecutive elements (one row)
    const int i    = base >> 11;         // row (NY = 2048)
    const int j    = base & (NYg - 1);   // column of first element

    const float4 c0 = *reinterpret_cast<const float4*>(u + base);
    const float4 c1 = *reinterpret_cast<const float4*>(u + base + 4);
    float4 L0, L1, R0, R1;
    if (i > 0) {
        L0 = *reinterpret_cast<const float4*>(u + base - NYg);
        L1 = *reinterpret_cast<const float4*>(u + base - NYg + 4);
    } else {
        L0 = L1 = make_float4(bc0, bc0, bc0, bc0);
    }
    if (i < NXg - 1) {
        R0 = *reinterpret_cast<const float4*>(u + base + NYg);
        R1 = *reinterpret_cast<const float4*>(u + base + NYg + 4);
    } else {
        R0 = R1 = make_float4(bc1, bc1, bc1, bc1);
    }
    const float um1 = (j > 0)       ? u[base - 1] : bc0;
    const float up8 = (j + 8 < NYg) ? u[base + 8] : bc1;

    const float uc[8] = {c0.x, c0.y, c0.z, c0.w, c1.x, c1.y, c1.z, c1.w};
    const float ul[8] = {L0.x, L0.y, L0.z, L0.w, L1.x, L1.y, L1.z, L1.w};
    const float ur[8] = {R0.x, R0.y, R0.z, R0.w, R1.x, R1.y, R1.z, R1.w};
    const float ub[8] = {um1,  c0.x, c0.y, c0.z, c0.w, c1.x, c1.y, c1.z};
    const float ut[8] = {c0.y, c0.z, c0.w, c1.x, c1.y, c1.z, c1.w, up8};

    float res[8];
    #pragma unroll
    for (int e = 0; e < 8; ++e) {
        // a(u): t = (u - LO)*SCALE
        float t = fmaf(uc[e], TAB_SCALE, TAB_BIAS);
        t = fminf(fmaxf(t, 0.0f), (float)TAB_N - 0.001f);
        const int   i0 = (int)t;
        const float fr = t - (float)i0;
        const float a  = fmaf(fr, sdel[i0], sval[i0]);

        const float ap = fmaxf(a, 0.0f);
        const float am = fminf(a, 0.0f);
        const float cp = fmaf(ap,  INV_D, d);   // d + relu(a)/DX
        const float cm = fmaf(am, -INV_D, d);   // d - (-relu(-a))/DX

        // gl+gb = 2*s0*uc + s1*(ul+ub); gr+gt = 2*s0*uc + s1*(ur+ut)
        const float g2 = two_s0 * uc[e];
        const float gp = fmaf(s1, ul[e] + ub[e], g2);
        const float gm = fmaf(s1, ur[e] + ut[e], g2);
        res[e] = fmaf(cm, gm, cp * gp);
    }
    f32x4 o0 = {res[0], res[1], res[2], res[3]};
    f32x4 o1 = {res[4], res[5], res[6], res[7]};
    __builtin_nontemporal_store(o0, reinterpret_cast<f32x4*>(out + base));
    __builtin_nontemporal_store(o1, reinterpret_cast<f32x4*>(out + base + 4));
}

extern "C" void kernel_launch(void* const* d_in, const int* in_sizes, int n_in,
                              void* d_out, int out_size, void* d_ws, size_t ws_size,
                              hipStream_t stream) {
    const float* u  = (const float*)d_in[0];
    const float* W1 = (const float*)d_in[1];
    const float* W2 = (const float*)d_in[2];
    const float* W3 = (const float*)d_in[3];
    const float* D  = (const float*)d_in[4];
    const float* BC = (const float*)d_in[5];
    const float* St = (const float*)d_in[6];
    float* out = (float*)d_out;
    float* tab = (float*)d_ws;   // (TAB_N+1) floats of scratch

    // 8 nodes per 256-thread block -> 257 blocks covers 2049 nodes.
    hipLaunchKernelGGL(build_table, dim3((TAB_N / 8) + 1), dim3(256), 0, stream,
                       W1, W2, W3, tab);

    const int n_threads = (NXg * NYg) / 8;           // 524,288
    hipLaunchKernelGGL(flux_kernel, dim3(n_threads / 1024), dim3(1024), 0, stream,
                       u, tab, D, BC, St, out);
}